// Round 1
// baseline (1574.445 us; speedup 1.0000x reference)
//
#include <hip/hip_runtime.h>
#include <hip/hip_bf16.h>

#define N_TOK 32768
#define D_IN 1024
#define D_OUT 1024
#define NE 8

#define BM 128
#define BN 128
#define BK 64
#define PAD 72  // halfword pitch: 144 B rows -> 16B aligned, ~2-way LDS conflicts (free)

typedef __attribute__((ext_vector_type(8))) short short8;
typedef __attribute__((ext_vector_type(4))) float floatx4;

__device__ __forceinline__ unsigned short f2bf(float f) {
    union { float f; unsigned u; } v; v.f = f;
    unsigned r = v.u + 0x7fffu + ((v.u >> 16) & 1u);  // RNE
    return (unsigned short)(r >> 16);
}
__device__ __forceinline__ float bf2f(unsigned short u) {
    union { unsigned u; float f; } v; v.u = ((unsigned)u) << 16;
    return v.f;
}

// ---------------- zero the routing counters (ws is poisoned 0xAA each call) ---
__global__ void zero_cnt(int* __restrict__ cnt) {
    if (threadIdx.x < 16) cnt[threadIdx.x] = 0;
}

// ---------------- We [e][i][o] fp32 -> WeT [e][o][i] bf16 ---------------------
__global__ __launch_bounds__(256) void transpose_we(
    const float* __restrict__ We, unsigned short* __restrict__ WeT)
{
    __shared__ unsigned short tile[64 * 65];
    int e = blockIdx.z;
    int i0 = blockIdx.x * 64, o0 = blockIdx.y * 64;
    const float* src = We + ((size_t)e * D_IN + i0) * D_OUT + o0;
#pragma unroll
    for (int it = 0; it < 16; ++it) {
        int idx = threadIdx.x + it * 256;      // 0..4095
        int r = idx >> 6, c = idx & 63;
        tile[r * 65 + c] = f2bf(src[(size_t)r * D_OUT + c]);
    }
    __syncthreads();
    unsigned short* dst = WeT + ((size_t)e * D_OUT + o0) * D_IN + i0;
#pragma unroll
    for (int it = 0; it < 16; ++it) {
        int idx = threadIdx.x + it * 256;
        int r = idx >> 6, c = idx & 63;
        dst[(size_t)r * D_IN + c] = tile[c * 65 + r];
    }
}

// ---------------- gating: logits (fp64 accum) -> tanh -> top2 -> softmax ------
__global__ __launch_bounds__(256) void gate_kernel(
    const float* __restrict__ x, const float* __restrict__ Wg,
    const float* __restrict__ bg,
    int* __restrict__ top_i, float* __restrict__ gates,
    int* __restrict__ cnt, int* __restrict__ lists)
{
    int wave = threadIdx.x >> 6, lane = threadIdx.x & 63;
    int token = blockIdx.x * 4 + wave;
    const float* xr = x + (size_t)token * D_IN;
    double acc[NE] = {};
    for (int jj = 0; jj < 16; ++jj) {
        int i = jj * 64 + lane;
        double xv = (double)xr[i];
        const float* wr = Wg + (size_t)i * NE;
#pragma unroll
        for (int e = 0; e < NE; ++e) acc[e] += xv * (double)wr[e];
    }
#pragma unroll
    for (int off = 32; off; off >>= 1) {
#pragma unroll
        for (int e = 0; e < NE; ++e) acc[e] += __shfl_xor(acc[e], off, 64);
    }
    if (lane == 0) {
        float lg[NE];
#pragma unroll
        for (int e = 0; e < NE; ++e) lg[e] = tanhf((float)(acc[e] + (double)bg[e]));
        int i0 = 0;
        for (int e = 1; e < NE; ++e) if (lg[e] > lg[i0]) i0 = e;  // lowest-index wins ties
        int i1 = (i0 == 0) ? 1 : 0;
        for (int e = 0; e < NE; ++e) { if (e == i0) continue; if (lg[e] > lg[i1]) i1 = e; }
        float t  = expf(lg[i1] - lg[i0]);
        float g0 = 1.0f / (1.0f + t);
        float g1 = t * g0;
        top_i[token * 2 + 0] = i0; top_i[token * 2 + 1] = i1;
        gates[token * 2 + 0] = g0; gates[token * 2 + 1] = g1;
        int p0 = atomicAdd(&cnt[i0], 1);
        lists[(size_t)i0 * N_TOK + p0] = token;
        int p1 = atomicAdd(&cnt[NE + i1], 1);
        lists[(size_t)(NE + i1) * N_TOK + p1] = token;
    }
}

// ---------------- gathered-token bf16 MFMA GEMM: h = x[toks] @ We[e] + be -----
// grid: (ntile=8, mtile<=256, expert=8); block 256 (4 waves, 2x2, 64x64 each)
__global__ __launch_bounds__(256) void gemm_slot(
    const float* __restrict__ x, const unsigned short* __restrict__ WeT,
    const float* __restrict__ be, const int* __restrict__ lists,
    const int* __restrict__ cnt, int slot, unsigned short* __restrict__ h)
{
    int e = blockIdx.z;
    int count = cnt[slot * NE + e];
    int m0 = blockIdx.y * BM;
    if (m0 >= count) return;
    int n0 = blockIdx.x * BN;
    const int* list = lists + (size_t)(slot * NE + e) * N_TOK;

    __shared__ int toks[BM];
    __shared__ unsigned short As[BM * PAD];
    __shared__ unsigned short Bs[BN * PAD];

    int tid = threadIdx.x;
    if (tid < BM) {
        int r = m0 + tid; if (r > count - 1) r = count - 1;  // tail duplicates last row
        toks[tid] = list[r];
    }
    __syncthreads();

    int lane = tid & 63, wave = tid >> 6;
    int wm = (wave & 1) * 64, wn = (wave >> 1) * 64;
    int q = lane & 15, quad = lane >> 4;

    floatx4 acc[4][4] = {};

    const unsigned short* Bglob = WeT + ((size_t)e * D_OUT + n0) * D_IN;

    for (int kb = 0; kb < D_IN; kb += BK) {
        // A: 128 rows x 64 k of fp32 x -> bf16 LDS
#pragma unroll
        for (int it = 0; it < 8; ++it) {
            int idx = tid + it * 256;          // 0..2047 float4s
            int m = idx >> 4, kq = idx & 15;
            float4 v = *(const float4*)(x + (size_t)toks[m] * D_IN + kb + kq * 4);
            ushort4 pk;
            pk.x = f2bf(v.x); pk.y = f2bf(v.y); pk.z = f2bf(v.z); pk.w = f2bf(v.w);
            *(ushort4*)&As[m * PAD + kq * 4] = pk;
        }
        // B: 128 rows (n) x 64 k of bf16 WeT -> LDS (straight copy, k-contiguous)
#pragma unroll
        for (int it = 0; it < 4; ++it) {
            int idx = tid + it * 256;          // 0..1023 uint4s (8 bf16 each)
            int n = idx >> 3, kq = idx & 7;
            *(uint4*)&Bs[n * PAD + kq * 8] =
                *(const uint4*)(Bglob + (size_t)n * D_IN + kb + kq * 8);
        }
        __syncthreads();

#pragma unroll
        for (int ks = 0; ks < BK; ks += 32) {
            short8 af[4], bfr[4];
#pragma unroll
            for (int i = 0; i < 4; ++i)
                af[i] = *(const short8*)&As[(wm + i * 16 + q) * PAD + ks + quad * 8];
#pragma unroll
            for (int j = 0; j < 4; ++j)
                bfr[j] = *(const short8*)&Bs[(wn + j * 16 + q) * PAD + ks + quad * 8];
#pragma unroll
            for (int i = 0; i < 4; ++i)
#pragma unroll
                for (int j = 0; j < 4; ++j)
                    acc[i][j] = __builtin_amdgcn_mfma_f32_16x16x32_bf16(
                        af[i], bfr[j], acc[i][j], 0, 0, 0);
        }
        __syncthreads();
    }

    // epilogue: + bias, store pre-GELU h (bf16) scattered by token
#pragma unroll
    for (int i = 0; i < 4; ++i) {
#pragma unroll
        for (int r = 0; r < 4; ++r) {
            int m = wm + i * 16 + quad * 4 + r;
            if (m0 + m < count) {
                int tok = toks[m];
#pragma unroll
                for (int j = 0; j < 4; ++j) {
                    int n = n0 + wn + j * 16 + q;
                    float v = acc[i][j][r] + be[(size_t)e * D_OUT + n];
                    h[(size_t)tok * D_OUT + n] = f2bf(v);
                }
            }
        }
    }
}

// ---------------- GELU(exact) + LayerNorm + gamma/beta + gated combine --------
__global__ __launch_bounds__(256) void ln_combine(
    const unsigned short* __restrict__ h, const float* __restrict__ gamma,
    const float* __restrict__ beta, const float* __restrict__ gates,
    const int* __restrict__ top_i, int slot, float* __restrict__ out)
{
    int wave = threadIdx.x >> 6, lane = threadIdx.x & 63;
    int token = blockIdx.x * 4 + wave;
    int e = top_i[token * 2 + slot];
    float gate = gates[token * 2 + slot];
    const unsigned short* hr = h + (size_t)token * D_OUT;

    float g[16], sum = 0.f, sumsq = 0.f;
#pragma unroll
    for (int jj = 0; jj < 16; ++jj) {
        int n = jj * 64 + lane;
        float v = bf2f(hr[n]);
        float gl = 0.5f * v * (1.0f + erff(v * 0.70710678118654752f));
        g[jj] = gl; sum += gl; sumsq += gl * gl;
    }
#pragma unroll
    for (int off = 32; off; off >>= 1) {
        sum   += __shfl_xor(sum, off, 64);
        sumsq += __shfl_xor(sumsq, off, 64);
    }
    float mu  = sum * (1.0f / 1024.0f);
    float var = sumsq * (1.0f / 1024.0f) - mu * mu;
    float rs  = rsqrtf(var + 1e-5f);

    const float* gm = gamma + (size_t)e * D_OUT;
    const float* bt = beta  + (size_t)e * D_OUT;
    float* orow = out + (size_t)token * D_OUT;
#pragma unroll
    for (int jj = 0; jj < 16; ++jj) {
        int n = jj * 64 + lane;
        float y = (g[jj] - mu) * rs * gm[n] + bt[n];
        float val = gate * y;
        if (slot == 0) orow[n] = val;
        else           orow[n] += val;
    }
}

extern "C" void kernel_launch(void* const* d_in, const int* in_sizes, int n_in,
                              void* d_out, int out_size, void* d_ws, size_t ws_size,
                              hipStream_t stream) {
    const float* x     = (const float*)d_in[0];
    const float* Wg    = (const float*)d_in[1];
    const float* bg    = (const float*)d_in[2];
    const float* We    = (const float*)d_in[3];
    const float* be    = (const float*)d_in[4];
    const float* gamma = (const float*)d_in[5];
    const float* beta  = (const float*)d_in[6];
    float* out = (float*)d_out;

    // ws layout (~86 MB):
    char* w = (char*)d_ws;
    size_t off = 0;
    int*   cnt   = (int*)(w + off);            off += 256;
    int*   top_i = (int*)(w + off);            off += (size_t)N_TOK * 2 * 4;
    float* gates = (float*)(w + off);          off += (size_t)N_TOK * 2 * 4;
    int*   lists = (int*)(w + off);            off += (size_t)16 * N_TOK * 4;
    unsigned short* WeT = (unsigned short*)(w + off); off += (size_t)NE * D_IN * D_OUT * 2;
    unsigned short* h   = (unsigned short*)(w + off); off += (size_t)N_TOK * D_OUT * 2;

    zero_cnt<<<1, 64, 0, stream>>>(cnt);
    transpose_we<<<dim3(16, 16, NE), 256, 0, stream>>>(We, WeT);
    gate_kernel<<<N_TOK / 4, 256, 0, stream>>>(x, Wg, bg, top_i, gates, cnt, lists);
    for (int s = 0; s < 2; ++s) {
        gemm_slot<<<dim3(D_OUT / BN, N_TOK / BM, NE), 256, 0, stream>>>(
            x, WeT, be, lists, cnt, s, h);
        ln_combine<<<N_TOK / 4, 256, 0, stream>>>(h, gamma, beta, gates, top_i, s, out);
    }
}

// Round 2
// 1447.964 us; speedup vs baseline: 1.0874x; 1.0874x over previous
//
#include <hip/hip_runtime.h>
#include <hip/hip_bf16.h>

#define N_TOK 32768
#define D_IN 1024
#define D_OUT 1024
#define NE 8

#define BM 128
#define BN 128
#define BK 64
#define PAD 72  // halfword pitch: 144 B rows -> 16B aligned, ~2-way LDS conflicts (free)

#define GTOK 32 // tokens per gate block (8 per wave)

typedef __attribute__((ext_vector_type(8))) short short8;
typedef __attribute__((ext_vector_type(4))) float floatx4;

__device__ __forceinline__ unsigned short f2bf(float f) {
    union { float f; unsigned u; } v; v.f = f;
    unsigned r = v.u + 0x7fffu + ((v.u >> 16) & 1u);  // RNE
    return (unsigned short)(r >> 16);
}
__device__ __forceinline__ float bf2f(unsigned short u) {
    union { unsigned u; float f; } v; v.u = ((unsigned)u) << 16;
    return v.f;
}

// ---------------- zero the routing counters (ws is poisoned 0xAA each call) ---
__global__ void zero_cnt(int* __restrict__ cnt) {
    if (threadIdx.x < 16) cnt[threadIdx.x] = 0;
}

// ---------------- We [e][i][o] fp32 -> WeT [e][o][i] bf16 ---------------------
__global__ __launch_bounds__(256) void transpose_we(
    const float* __restrict__ We, unsigned short* __restrict__ WeT)
{
    __shared__ unsigned short tile[64 * 65];
    int e = blockIdx.z;
    int i0 = blockIdx.x * 64, o0 = blockIdx.y * 64;
    const float* src = We + ((size_t)e * D_IN + i0) * D_OUT + o0;
#pragma unroll
    for (int it = 0; it < 16; ++it) {
        int idx = threadIdx.x + it * 256;      // 0..4095
        int r = idx >> 6, c = idx & 63;
        tile[r * 65 + c] = f2bf(src[(size_t)r * D_OUT + c]);
    }
    __syncthreads();
    unsigned short* dst = WeT + ((size_t)e * D_OUT + o0) * D_IN + i0;
#pragma unroll
    for (int it = 0; it < 16; ++it) {
        int idx = threadIdx.x + it * 256;
        int r = idx >> 6, c = idx & 63;
        dst[(size_t)r * D_IN + c] = tile[c * 65 + r];
    }
}

// ---------------- gating: LDS-staged Wg, fp64 accum, top2, softmax ------------
// Also converts x -> bf16 (xb) for the GEMM A-operand (fused, saves a pass).
__global__ __launch_bounds__(256) void gate_kernel(
    const float* __restrict__ x, const float* __restrict__ Wg,
    const float* __restrict__ bg,
    int* __restrict__ top_i, float* __restrict__ gates,
    int* __restrict__ cnt, int* __restrict__ lists,
    unsigned short* __restrict__ xb)
{
    __shared__ float wg_s[D_IN * 9];   // pad 8->9: lane stride 18 banks -> 2-way (free)
    int tid = threadIdx.x;
    for (int idx = tid; idx < D_IN * NE; idx += 256) {
        int r = idx >> 3, e = idx & 7;
        wg_s[r * 9 + e] = Wg[idx];     // coalesced global read
    }
    __syncthreads();

    int wave = tid >> 6, lane = tid & 63;
#pragma unroll 1
    for (int t = 0; t < GTOK / 4; ++t) {
        int token = blockIdx.x * GTOK + t * 4 + wave;
        const float* xr = x + (size_t)token * D_IN;
        unsigned short* xbr = xb + (size_t)token * D_IN;
        double acc[NE] = {};
#pragma unroll
        for (int jj = 0; jj < 8; ++jj) {
            int i = jj * 128 + lane * 2;
            float2 v = *(const float2*)(xr + i);
            unsigned short b0 = f2bf(v.x), b1 = f2bf(v.y);
            *(unsigned*)(xbr + i) = (unsigned)b0 | ((unsigned)b1 << 16);
            const float* w0 = &wg_s[(size_t)i * 9];
#pragma unroll
            for (int e = 0; e < NE; ++e)
                acc[e] += (double)v.x * (double)w0[e] + (double)v.y * (double)w0[9 + e];
        }
#pragma unroll
        for (int off = 32; off; off >>= 1) {
#pragma unroll
            for (int e = 0; e < NE; ++e) acc[e] += __shfl_xor(acc[e], off, 64);
        }
        if (lane == 0) {
            float lg[NE];
#pragma unroll
            for (int e = 0; e < NE; ++e) lg[e] = tanhf((float)(acc[e] + (double)bg[e]));
            int i0 = 0;
            for (int e = 1; e < NE; ++e) if (lg[e] > lg[i0]) i0 = e;  // lowest idx wins ties
            int i1 = (i0 == 0) ? 1 : 0;
            for (int e = 0; e < NE; ++e) { if (e == i0) continue; if (lg[e] > lg[i1]) i1 = e; }
            float tt = expf(lg[i1] - lg[i0]);
            float g0 = 1.0f / (1.0f + tt);
            float g1 = tt * g0;
            top_i[token * 2 + 0] = i0; top_i[token * 2 + 1] = i1;
            gates[token * 2 + 0] = g0; gates[token * 2 + 1] = g1;
            int p0 = atomicAdd(&cnt[i0], 1);
            lists[(size_t)i0 * N_TOK + p0] = token;
            int p1 = atomicAdd(&cnt[NE + i1], 1);
            lists[(size_t)(NE + i1) * N_TOK + p1] = token;
        }
    }
}

// ---------------- gathered-token bf16 MFMA GEMM: h = x[toks] @ We[e] + be -----
// grid: (ntile=8, mtile<=256, expert=8); block 256 (4 waves, 2x2, 64x64 each)
// USEBF: A-operand from precomputed bf16 xb (straight copy) vs fp32 x (convert).
template <bool USEBF>
__global__ __launch_bounds__(256) void gemm_slot(
    const float* __restrict__ x, const unsigned short* __restrict__ xb,
    const unsigned short* __restrict__ WeT,
    const float* __restrict__ be, const int* __restrict__ lists,
    const int* __restrict__ cnt, int slot, unsigned short* __restrict__ h)
{
    int e = blockIdx.z;
    int count = cnt[slot * NE + e];
    int m0 = blockIdx.y * BM;
    if (m0 >= count) return;
    int n0 = blockIdx.x * BN;
    const int* list = lists + (size_t)(slot * NE + e) * N_TOK;

    __shared__ int toks[BM];
    __shared__ unsigned short As[BM * PAD];
    __shared__ unsigned short Bs[BN * PAD];

    int tid = threadIdx.x;
    if (tid < BM) {
        int r = m0 + tid; if (r > count - 1) r = count - 1;  // tail duplicates last row
        toks[tid] = list[r];
    }
    __syncthreads();

    int lane = tid & 63, wave = tid >> 6;
    int wm = (wave & 1) * 64, wn = (wave >> 1) * 64;
    int q = lane & 15, quad = lane >> 4;

    floatx4 acc[4][4] = {};

    const unsigned short* Bglob = WeT + ((size_t)e * D_OUT + n0) * D_IN;

    for (int kb = 0; kb < D_IN; kb += BK) {
        if (USEBF) {
            // A: 128 rows x 64 k bf16 -> LDS, straight uint4 copy
#pragma unroll
            for (int it = 0; it < 4; ++it) {
                int idx = tid + it * 256;      // 0..1023 uint4s
                int m = idx >> 3, kq = idx & 7;
                *(uint4*)&As[m * PAD + kq * 8] =
                    *(const uint4*)(xb + (size_t)toks[m] * D_IN + kb + kq * 8);
            }
        } else {
            // A: 128 rows x 64 k fp32 -> bf16 LDS
#pragma unroll
            for (int it = 0; it < 8; ++it) {
                int idx = tid + it * 256;      // 0..2047 float4s
                int m = idx >> 4, kq = idx & 15;
                float4 v = *(const float4*)(x + (size_t)toks[m] * D_IN + kb + kq * 4);
                ushort4 pk;
                pk.x = f2bf(v.x); pk.y = f2bf(v.y); pk.z = f2bf(v.z); pk.w = f2bf(v.w);
                *(ushort4*)&As[m * PAD + kq * 4] = pk;
            }
        }
        // B: 128 n-rows x 64 k bf16 WeT -> LDS (k-contiguous copy)
#pragma unroll
        for (int it = 0; it < 4; ++it) {
            int idx = tid + it * 256;          // 0..1023 uint4s
            int n = idx >> 3, kq = idx & 7;
            *(uint4*)&Bs[n * PAD + kq * 8] =
                *(const uint4*)(Bglob + (size_t)n * D_IN + kb + kq * 8);
        }
        __syncthreads();

#pragma unroll
        for (int ks = 0; ks < BK; ks += 32) {
            short8 af[4], bfr[4];
#pragma unroll
            for (int i = 0; i < 4; ++i)
                af[i] = *(const short8*)&As[(wm + i * 16 + q) * PAD + ks + quad * 8];
#pragma unroll
            for (int j = 0; j < 4; ++j)
                bfr[j] = *(const short8*)&Bs[(wn + j * 16 + q) * PAD + ks + quad * 8];
#pragma unroll
            for (int i = 0; i < 4; ++i)
#pragma unroll
                for (int j = 0; j < 4; ++j)
                    acc[i][j] = __builtin_amdgcn_mfma_f32_16x16x32_bf16(
                        af[i], bfr[j], acc[i][j], 0, 0, 0);
        }
        __syncthreads();
    }

    // epilogue: + bias, store pre-GELU h (bf16) scattered by token
#pragma unroll
    for (int i = 0; i < 4; ++i) {
#pragma unroll
        for (int r = 0; r < 4; ++r) {
            int m = wm + i * 16 + quad * 4 + r;
            if (m0 + m < count) {
                int tok = toks[m];
#pragma unroll
                for (int j = 0; j < 4; ++j) {
                    int n = n0 + wn + j * 16 + q;
                    float v = acc[i][j][r] + be[(size_t)e * D_OUT + n];
                    h[(size_t)tok * D_OUT + n] = f2bf(v);
                }
            }
        }
    }
}

// ---------------- GELU(exact) + LayerNorm + gamma/beta + gated combine --------
__global__ __launch_bounds__(256) void ln_combine(
    const unsigned short* __restrict__ h, const float* __restrict__ gamma,
    const float* __restrict__ beta, const float* __restrict__ gates,
    const int* __restrict__ top_i, int slot, float* __restrict__ out)
{
    int wave = threadIdx.x >> 6, lane = threadIdx.x & 63;
    int token = blockIdx.x * 4 + wave;
    int e = top_i[token * 2 + slot];
    float gate = gates[token * 2 + slot];
    const unsigned short* hr = h + (size_t)token * D_OUT;

    float g[16], sum = 0.f, sumsq = 0.f;
#pragma unroll
    for (int jj = 0; jj < 16; ++jj) {
        int n = jj * 64 + lane;
        float v = bf2f(hr[n]);
        float gl = 0.5f * v * (1.0f + erff(v * 0.70710678118654752f));
        g[jj] = gl; sum += gl; sumsq += gl * gl;
    }
#pragma unroll
    for (int off = 32; off; off >>= 1) {
        sum   += __shfl_xor(sum, off, 64);
        sumsq += __shfl_xor(sumsq, off, 64);
    }
    float mu  = sum * (1.0f / 1024.0f);
    float var = sumsq * (1.0f / 1024.0f) - mu * mu;
    float rs  = rsqrtf(var + 1e-5f);

    const float* gm = gamma + (size_t)e * D_OUT;
    const float* bt = beta  + (size_t)e * D_OUT;
    float* orow = out + (size_t)token * D_OUT;
#pragma unroll
    for (int jj = 0; jj < 16; ++jj) {
        int n = jj * 64 + lane;
        float y = (g[jj] - mu) * rs * gm[n] + bt[n];
        float val = gate * y;
        if (slot == 0) orow[n] = val;
        else           orow[n] += val;
    }
}

extern "C" void kernel_launch(void* const* d_in, const int* in_sizes, int n_in,
                              void* d_out, int out_size, void* d_ws, size_t ws_size,
                              hipStream_t stream) {
    const float* x     = (const float*)d_in[0];
    const float* Wg    = (const float*)d_in[1];
    const float* bg    = (const float*)d_in[2];
    const float* We    = (const float*)d_in[3];
    const float* be    = (const float*)d_in[4];
    const float* gamma = (const float*)d_in[5];
    const float* beta  = (const float*)d_in[6];
    float* out = (float*)d_out;

    char* w = (char*)d_ws;
    size_t off = 0;
    int*   cnt   = (int*)(w + off);            off += 256;
    int*   top_i = (int*)(w + off);            off += (size_t)N_TOK * 2 * 4;
    float* gates = (float*)(w + off);          off += (size_t)N_TOK * 2 * 4;
    int*   lists = (int*)(w + off);            off += (size_t)16 * N_TOK * 4;
    unsigned short* WeT = (unsigned short*)(w + off); off += (size_t)NE * D_IN * D_OUT * 2;
    unsigned short* h   = (unsigned short*)(w + off); off += (size_t)N_TOK * D_OUT * 2;
    size_t xb_bytes = (size_t)N_TOK * D_IN * 2;
    bool use_bf = (off + xb_bytes) <= ws_size;
    // fallback: gate still needs a valid xb target; alias h (fully overwritten
    // by slot-0 gemm before ln_combine reads it, so the garbage is harmless)
    unsigned short* xb = use_bf ? (unsigned short*)(w + off) : h;
    if (use_bf) off += xb_bytes;

    zero_cnt<<<1, 64, 0, stream>>>(cnt);
    transpose_we<<<dim3(16, 16, NE), 256, 0, stream>>>(We, WeT);
    gate_kernel<<<N_TOK / GTOK, 256, 0, stream>>>(x, Wg, bg, top_i, gates, cnt, lists, xb);
    for (int s = 0; s < 2; ++s) {
        if (use_bf)
            gemm_slot<true><<<dim3(D_OUT / BN, N_TOK / BM, NE), 256, 0, stream>>>(
                x, xb, WeT, be, lists, cnt, s, h);
        else
            gemm_slot<false><<<dim3(D_OUT / BN, N_TOK / BM, NE), 256, 0, stream>>>(
                x, xb, WeT, be, lists, cnt, s, h);
        ln_combine<<<N_TOK / 4, 256, 0, stream>>>(h, gamma, beta, gates, top_i, s, out);
    }
}

// Round 3
// 816.091 us; speedup vs baseline: 1.9293x; 1.7743x over previous
//
#include <hip/hip_runtime.h>
#include <hip/hip_bf16.h>

#define N_TOK 32768
#define D_IN 1024
#define D_OUT 1024
#define NE 8

#define BM 128
#define BN 128
#define BK 64
#define PAD 72  // halfword pitch: 144 B rows -> 16B aligned, ~2-way LDS conflicts (free)

#define GTOK 32    // tokens per gate block (8 per wave)
#define CNT_STRIDE 64  // ints; pads each routing counter to its own 256B cache line

typedef __attribute__((ext_vector_type(8))) short short8;
typedef __attribute__((ext_vector_type(4))) float floatx4;

__device__ __forceinline__ unsigned short f2bf(float f) {
    union { float f; unsigned u; } v; v.f = f;
    unsigned r = v.u + 0x7fffu + ((v.u >> 16) & 1u);  // RNE
    return (unsigned short)(r >> 16);
}
__device__ __forceinline__ float bf2f(unsigned short u) {
    union { unsigned u; float f; } v; v.u = ((unsigned)u) << 16;
    return v.f;
}

// ---------------- zero the padded routing counters ----------------------------
__global__ void zero_cnt(int* __restrict__ cnt) {
    int i = blockIdx.x * 256 + threadIdx.x;
    if (i < 16 * CNT_STRIDE) cnt[i] = 0;
}

// ---------------- We [e][i][o] fp32 -> WeT [e][o][i] bf16 ---------------------
__global__ __launch_bounds__(256) void transpose_we(
    const float* __restrict__ We, unsigned short* __restrict__ WeT)
{
    __shared__ unsigned short tile[64 * 65];
    int e = blockIdx.z;
    int i0 = blockIdx.x * 64, o0 = blockIdx.y * 64;
    const float* src = We + ((size_t)e * D_IN + i0) * D_OUT + o0;
#pragma unroll
    for (int it = 0; it < 16; ++it) {
        int idx = threadIdx.x + it * 256;      // 0..4095
        int r = idx >> 6, c = idx & 63;
        tile[r * 65 + c] = f2bf(src[(size_t)r * D_OUT + c]);
    }
    __syncthreads();
    unsigned short* dst = WeT + ((size_t)e * D_OUT + o0) * D_IN + i0;
#pragma unroll
    for (int it = 0; it < 16; ++it) {
        int idx = threadIdx.x + it * 256;
        int r = idx >> 6, c = idx & 63;
        dst[(size_t)r * D_IN + c] = tile[c * 65 + r];
    }
}

// ---------------- gating: LDS Wg, fp64 accum, top2, softmax -------------------
// Routing lists built via per-block LDS histogram; only 16 padded global
// atomics per block (was 64 same-cache-line atomics -> global serialization).
// Also converts x -> bf16 (xb) for the GEMM A-operand.
__global__ __launch_bounds__(256) void gate_kernel(
    const float* __restrict__ x, const float* __restrict__ Wg,
    const float* __restrict__ bg,
    int* __restrict__ top_i, float* __restrict__ gates,
    int* __restrict__ cnt, int* __restrict__ lists,
    unsigned short* __restrict__ xb)
{
    __shared__ float wg_s[D_IN * 9];   // pad 8->9
    __shared__ int lcnt[16];
    __shared__ int lbase[16];
    __shared__ int ltoks[16][GTOK];
    int tid = threadIdx.x;
    if (tid < 16) lcnt[tid] = 0;
    for (int idx = tid; idx < D_IN * NE; idx += 256) {
        int r = idx >> 3, e = idx & 7;
        wg_s[r * 9 + e] = Wg[idx];     // coalesced global read
    }
    __syncthreads();

    int wave = tid >> 6, lane = tid & 63;
#pragma unroll 1
    for (int t = 0; t < GTOK / 4; ++t) {
        int token = blockIdx.x * GTOK + t * 4 + wave;
        const float* xr = x + (size_t)token * D_IN;
        unsigned short* xbr = xb + (size_t)token * D_IN;
        double acc[NE] = {};
#pragma unroll
        for (int jj = 0; jj < 8; ++jj) {
            int i = jj * 128 + lane * 2;
            float2 v = *(const float2*)(xr + i);
            unsigned short b0 = f2bf(v.x), b1 = f2bf(v.y);
            *(unsigned*)(xbr + i) = (unsigned)b0 | ((unsigned)b1 << 16);
            const float* w0 = &wg_s[(size_t)i * 9];
#pragma unroll
            for (int e = 0; e < NE; ++e)
                acc[e] += (double)v.x * (double)w0[e] + (double)v.y * (double)w0[9 + e];
        }
#pragma unroll
        for (int off = 32; off; off >>= 1) {
#pragma unroll
            for (int e = 0; e < NE; ++e) acc[e] += __shfl_xor(acc[e], off, 64);
        }
        if (lane == 0) {
            float lg[NE];
#pragma unroll
            for (int e = 0; e < NE; ++e) lg[e] = tanhf((float)(acc[e] + (double)bg[e]));
            int i0 = 0;
            for (int e = 1; e < NE; ++e) if (lg[e] > lg[i0]) i0 = e;  // lowest idx wins ties
            int i1 = (i0 == 0) ? 1 : 0;
            for (int e = 0; e < NE; ++e) { if (e == i0) continue; if (lg[e] > lg[i1]) i1 = e; }
            float tt = expf(lg[i1] - lg[i0]);
            float g0 = 1.0f / (1.0f + tt);
            float g1 = tt * g0;
            top_i[token * 2 + 0] = i0; top_i[token * 2 + 1] = i1;
            gates[token * 2 + 0] = g0; gates[token * 2 + 1] = g1;
            int p0 = atomicAdd(&lcnt[i0], 1);      // LDS atomic: cheap
            ltoks[i0][p0] = token;
            int p1 = atomicAdd(&lcnt[NE + i1], 1);
            ltoks[NE + i1][p1] = token;
        }
    }
    __syncthreads();
    if (tid < 16) lbase[tid] = atomicAdd(&cnt[tid * CNT_STRIDE], lcnt[tid]);
    __syncthreads();
    int g = tid >> 4, j = tid & 15;                // 16 threads per group
    int n = lcnt[g];
    int* dst = lists + (size_t)g * N_TOK + lbase[g];
    for (int k = j; k < n; k += 16) dst[k] = ltoks[g][k];
}

// ---------------- gathered-token bf16 MFMA GEMM: h = x[toks] @ We[e] + be -----
// grid: (ntile=8, mtile<=256, expert=8); block 256 (4 waves, 2x2, 64x64 each)
template <bool USEBF>
__global__ __launch_bounds__(256) void gemm_slot(
    const float* __restrict__ x, const unsigned short* __restrict__ xb,
    const unsigned short* __restrict__ WeT,
    const float* __restrict__ be, const int* __restrict__ lists,
    const int* __restrict__ cnt, int slot, unsigned short* __restrict__ h)
{
    int e = blockIdx.z;
    int count = cnt[(slot * NE + e) * CNT_STRIDE];
    int m0 = blockIdx.y * BM;
    if (m0 >= count) return;
    int n0 = blockIdx.x * BN;
    const int* list = lists + (size_t)(slot * NE + e) * N_TOK;

    __shared__ int toks[BM];
    __shared__ unsigned short As[BM * PAD];
    __shared__ unsigned short Bs[BN * PAD];

    int tid = threadIdx.x;
    if (tid < BM) {
        int r = m0 + tid; if (r > count - 1) r = count - 1;  // tail duplicates last row
        toks[tid] = list[r];
    }
    __syncthreads();

    int lane = tid & 63, wave = tid >> 6;
    int wm = (wave & 1) * 64, wn = (wave >> 1) * 64;
    int q = lane & 15, quad = lane >> 4;

    floatx4 acc[4][4] = {};

    const unsigned short* Bglob = WeT + ((size_t)e * D_OUT + n0) * D_IN;

    for (int kb = 0; kb < D_IN; kb += BK) {
        if (USEBF) {
#pragma unroll
            for (int it = 0; it < 4; ++it) {
                int idx = tid + it * 256;      // 0..1023 uint4s
                int m = idx >> 3, kq = idx & 7;
                *(uint4*)&As[m * PAD + kq * 8] =
                    *(const uint4*)(xb + (size_t)toks[m] * D_IN + kb + kq * 8);
            }
        } else {
#pragma unroll
            for (int it = 0; it < 8; ++it) {
                int idx = tid + it * 256;      // 0..2047 float4s
                int m = idx >> 4, kq = idx & 15;
                float4 v = *(const float4*)(x + (size_t)toks[m] * D_IN + kb + kq * 4);
                ushort4 pk;
                pk.x = f2bf(v.x); pk.y = f2bf(v.y); pk.z = f2bf(v.z); pk.w = f2bf(v.w);
                *(ushort4*)&As[m * PAD + kq * 4] = pk;
            }
        }
#pragma unroll
        for (int it = 0; it < 4; ++it) {
            int idx = tid + it * 256;          // 0..1023 uint4s
            int n = idx >> 3, kq = idx & 7;
            *(uint4*)&Bs[n * PAD + kq * 8] =
                *(const uint4*)(Bglob + (size_t)n * D_IN + kb + kq * 8);
        }
        __syncthreads();

#pragma unroll
        for (int ks = 0; ks < BK; ks += 32) {
            short8 af[4], bfr[4];
#pragma unroll
            for (int i = 0; i < 4; ++i)
                af[i] = *(const short8*)&As[(wm + i * 16 + q) * PAD + ks + quad * 8];
#pragma unroll
            for (int j = 0; j < 4; ++j)
                bfr[j] = *(const short8*)&Bs[(wn + j * 16 + q) * PAD + ks + quad * 8];
#pragma unroll
            for (int i = 0; i < 4; ++i)
#pragma unroll
                for (int j = 0; j < 4; ++j)
                    acc[i][j] = __builtin_amdgcn_mfma_f32_16x16x32_bf16(
                        af[i], bfr[j], acc[i][j], 0, 0, 0);
        }
        __syncthreads();
    }

#pragma unroll
    for (int i = 0; i < 4; ++i) {
#pragma unroll
        for (int r = 0; r < 4; ++r) {
            int m = wm + i * 16 + quad * 4 + r;
            if (m0 + m < count) {
                int tok = toks[m];
#pragma unroll
                for (int j = 0; j < 4; ++j) {
                    int n = n0 + wn + j * 16 + q;
                    float v = acc[i][j][r] + be[(size_t)e * D_OUT + n];
                    h[(size_t)tok * D_OUT + n] = f2bf(v);
                }
            }
        }
    }
}

// ---------------- GELU(exact) + LayerNorm + gamma/beta + gated combine --------
__global__ __launch_bounds__(256) void ln_combine(
    const unsigned short* __restrict__ h, const float* __restrict__ gamma,
    const float* __restrict__ beta, const float* __restrict__ gates,
    const int* __restrict__ top_i, int slot, float* __restrict__ out)
{
    int wave = threadIdx.x >> 6, lane = threadIdx.x & 63;
    int token = blockIdx.x * 4 + wave;
    int e = top_i[token * 2 + slot];
    float gate = gates[token * 2 + slot];
    const unsigned short* hr = h + (size_t)token * D_OUT;

    float g[16], sum = 0.f, sumsq = 0.f;
#pragma unroll
    for (int jj = 0; jj < 4; ++jj) {
        int n = jj * 256 + lane * 4;
        uint2 pk = *(const uint2*)(hr + n);    // 4 bf16
        float v0 = bf2f((unsigned short)(pk.x & 0xffff));
        float v1 = bf2f((unsigned short)(pk.x >> 16));
        float v2 = bf2f((unsigned short)(pk.y & 0xffff));
        float v3 = bf2f((unsigned short)(pk.y >> 16));
        float g0 = 0.5f * v0 * (1.0f + erff(v0 * 0.70710678118654752f));
        float g1 = 0.5f * v1 * (1.0f + erff(v1 * 0.70710678118654752f));
        float g2 = 0.5f * v2 * (1.0f + erff(v2 * 0.70710678118654752f));
        float g3 = 0.5f * v3 * (1.0f + erff(v3 * 0.70710678118654752f));
        g[jj * 4 + 0] = g0; g[jj * 4 + 1] = g1; g[jj * 4 + 2] = g2; g[jj * 4 + 3] = g3;
        sum   += g0 + g1 + g2 + g3;
        sumsq += g0 * g0 + g1 * g1 + g2 * g2 + g3 * g3;
    }
#pragma unroll
    for (int off = 32; off; off >>= 1) {
        sum   += __shfl_xor(sum, off, 64);
        sumsq += __shfl_xor(sumsq, off, 64);
    }
    float mu  = sum * (1.0f / 1024.0f);
    float var = sumsq * (1.0f / 1024.0f) - mu * mu;
    float rs  = rsqrtf(var + 1e-5f);

    const float* gm = gamma + (size_t)e * D_OUT;
    const float* bt = beta  + (size_t)e * D_OUT;
    float* orow = out + (size_t)token * D_OUT;
#pragma unroll
    for (int jj = 0; jj < 4; ++jj) {
        int n = jj * 256 + lane * 4;
        float4 gm4 = *(const float4*)(gm + n);
        float4 bt4 = *(const float4*)(bt + n);
        float4 o;
        o.x = gate * ((g[jj * 4 + 0] - mu) * rs * gm4.x + bt4.x);
        o.y = gate * ((g[jj * 4 + 1] - mu) * rs * gm4.y + bt4.y);
        o.z = gate * ((g[jj * 4 + 2] - mu) * rs * gm4.z + bt4.z);
        o.w = gate * ((g[jj * 4 + 3] - mu) * rs * gm4.w + bt4.w);
        if (slot == 0) {
            *(float4*)(orow + n) = o;
        } else {
            float4 p = *(const float4*)(orow + n);
            p.x += o.x; p.y += o.y; p.z += o.z; p.w += o.w;
            *(float4*)(orow + n) = p;
        }
    }
}

extern "C" void kernel_launch(void* const* d_in, const int* in_sizes, int n_in,
                              void* d_out, int out_size, void* d_ws, size_t ws_size,
                              hipStream_t stream) {
    const float* x     = (const float*)d_in[0];
    const float* Wg    = (const float*)d_in[1];
    const float* bg    = (const float*)d_in[2];
    const float* We    = (const float*)d_in[3];
    const float* be    = (const float*)d_in[4];
    const float* gamma = (const float*)d_in[5];
    const float* beta  = (const float*)d_in[6];
    float* out = (float*)d_out;

    char* w = (char*)d_ws;
    size_t off = 0;
    int*   cnt   = (int*)(w + off);            off += (size_t)16 * CNT_STRIDE * 4;
    int*   top_i = (int*)(w + off);            off += (size_t)N_TOK * 2 * 4;
    float* gates = (float*)(w + off);          off += (size_t)N_TOK * 2 * 4;
    int*   lists = (int*)(w + off);            off += (size_t)16 * N_TOK * 4;
    unsigned short* WeT = (unsigned short*)(w + off); off += (size_t)NE * D_IN * D_OUT * 2;
    unsigned short* h   = (unsigned short*)(w + off); off += (size_t)N_TOK * D_OUT * 2;
    size_t xb_bytes = (size_t)N_TOK * D_IN * 2;
    bool use_bf = (off + xb_bytes) <= ws_size;
    unsigned short* xb = use_bf ? (unsigned short*)(w + off) : h;
    if (use_bf) off += xb_bytes;

    zero_cnt<<<(16 * CNT_STRIDE + 255) / 256, 256, 0, stream>>>(cnt);
    transpose_we<<<dim3(16, 16, NE), 256, 0, stream>>>(We, WeT);
    gate_kernel<<<N_TOK / GTOK, 256, 0, stream>>>(x, Wg, bg, top_i, gates, cnt, lists, xb);
    for (int s = 0; s < 2; ++s) {
        if (use_bf)
            gemm_slot<true><<<dim3(D_OUT / BN, N_TOK / BM, NE), 256, 0, stream>>>(
                x, xb, WeT, be, lists, cnt, s, h);
        else
            gemm_slot<false><<<dim3(D_OUT / BN, N_TOK / BM, NE), 256, 0, stream>>>(
                x, xb, WeT, be, lists, cnt, s, h);
        ln_combine<<<N_TOK / 4, 256, 0, stream>>>(h, gamma, beta, gates, top_i, s, out);
    }
}